// Round 9
// baseline (252.422 us; speedup 1.0000x reference)
//
#include <hip/hip_runtime.h>

// GCN edge predictor, collapsed to scalar-per-node linear algebra:
//   u_i = x_i . w1c ;  v = A u + c1 ;  t = A v + c2 ;  out[g] = sum_g t + c0
//   A = D^-1/2 (Adj + I) D^-1/2
// R13: balance/occupancy attack on ALL four edge-scale passes.
//   Evidence: every pass ~45-50us regardless of inner structure; grids of
//   391-782 blocks (1.5-3.05 blocks/CU) starve latency hiding.
//   - scatter: 2048-edge tiles -> 1563 blocks (~6/CU), 1 quad/thread.
//   - degree/mid/final: bucket split x2 -> 1564 blocks; LDS accumulate
//     then 128 COALESCED global atomicAdds/block (200K total, 8 lines/blk).
//   - micro finishers (n-scale): finA dinv/w/out-init, finB v/wb, finC t+pool.
//   Pipeline: memset(4KB) + scatter + degpart + finA + midpart + finB +
//   finalpart + finC. 4 edge passes, 3 micro, 1 fill.

#define RSHIFT 7
#define RNODES 128           // nodes per bucket
#define NB_MAX 1024          // max buckets (n <= 131072; src fits 17 bits)
#define STHREADS 512
#define CTHREADS 512
#define TILE_E 2048          // edges per scatter tile (4 per thread)
#define BCAP 6144            // per-bucket slab capacity (mean ~4092, +32 sigma)

// Fused: weight collapse (block-redundant) + u + zero(degG/accG/acc2G) +
// single-quad direct scatter.
__global__ __launch_bounds__(STHREADS, 4)
void scatter_k(const float* __restrict__ x,
               const int* __restrict__ src, const int* __restrict__ dst,
               const float* __restrict__ W1, const float* __restrict__ b1,
               const float* __restrict__ W2, const float* __restrict__ b2,
               const float* __restrict__ Wf1, const float* __restrict__ bf1,
               const float* __restrict__ Wf2, const float* __restrict__ bf2,
               const float* __restrict__ Wf3, const float* __restrict__ bf3,
               const float* __restrict__ Wo, const float* __restrict__ bo,
               float* __restrict__ u, float* __restrict__ scG,
               int* __restrict__ degG, float* __restrict__ accG,
               float* __restrict__ acc2G,
               int E, int n, int npb, int nb,
               int* __restrict__ cursor, unsigned int* __restrict__ binned) {
    __shared__ int hist[NB_MAX];
    __shared__ int lbase[NB_MAX];
    __shared__ float wtmp[224];
    __shared__ float w1c_s[64];
    const int tid = threadIdx.x;
    const int bx = blockIdx.x;

    // ---- weight collapse (redundant per block; ~9K MACs) ----
    {
        float* wo  = wtmp;         // 10
        float* w3  = wtmp + 16;    // 20
        float* w2  = wtmp + 48;    // 30
        float* w1  = wtmp + 80;    // 50
        float* w2c = wtmp + 144;   // 60
        hist[tid] = 0; hist[tid + STHREADS] = 0;
        if (tid < 10) wo[tid] = Wo[tid];
        __syncthreads();
        if (tid < 20) { float s = 0.f; for (int j = 0; j < 10; ++j) s += Wf3[tid*10+j]*wo[j]; w3[tid] = s; }
        __syncthreads();
        if (tid < 30) { float s = 0.f; for (int j = 0; j < 20; ++j) s += Wf2[tid*20+j]*w3[j]; w2[tid] = s; }
        __syncthreads();
        if (tid < 50) { float s = 0.f; for (int j = 0; j < 30; ++j) s += Wf1[tid*30+j]*w2[j]; w1[tid] = s; }
        __syncthreads();
        if (tid < 60) { float s = 0.f; for (int j = 0; j < 50; ++j) s += W2[tid*50+j]*w1[j]; w2c[tid] = s; }
        __syncthreads();
        if (tid < 64) { float s = 0.f; for (int j = 0; j < 60; ++j) s += W1[tid*60+j]*w2c[j]; w1c_s[tid] = s; }
        if (bx == 0 && tid == 0) {
            float c1 = 0.f; for (int j = 0; j < 60; ++j) c1 += b1[j]*w2c[j];
            float c2 = 0.f; for (int j = 0; j < 50; ++j) c2 += b2[j]*w1[j];
            float c0 = bo[0];
            for (int j = 0; j < 30; ++j) c0 += bf1[j]*w2[j];
            for (int j = 0; j < 20; ++j) c0 += bf2[j]*w3[j];
            for (int j = 0; j < 10; ++j) c0 += bf3[j]*wo[j];
            scG[0] = c1; scG[1] = c2; scG[2] = c0;
        }
        __syncthreads();
    }

    // ---- zero accumulators + u for nodes [bx*npb, bx*npb+npb) ----
    {
        int base = bx * npb;
        for (int i = tid; i < npb; i += STHREADS) {
            int g = base + i;
            if (g < n) { degG[g] = 0; accG[g] = 0.f; acc2G[g] = 0.f; }
        }
        const int grp = tid >> 4, sub = tid & 15;
        float4 wv = *reinterpret_cast<const float4*>(&w1c_s[sub * 4]);
        for (int p = 0; p * 32 < npb; ++p) {
            int nl = p * 32 + grp;
            int g = base + nl;
            bool ok = (nl < npb) && (g < n);
            float val = 0.f;
            if (ok) {
                float4 xv = *reinterpret_cast<const float4*>(
                    x + (size_t)g * 64 + sub * 4);
                val = xv.x*wv.x + xv.y*wv.y + xv.z*wv.z + xv.w*wv.w;
            }
            val += __shfl_down(val, 8, 16);
            val += __shfl_down(val, 4, 16);
            val += __shfl_down(val, 2, 16);
            val += __shfl_down(val, 1, 16);
            if (ok && sub == 0) u[g] = val;
        }
    }

    // ---- scatter tile bx: 4 edges/thread (one quad), named scalars ----
    int e0 = bx * TILE_E;
    int e1 = e0 + TILE_E; if (e1 > E) e1 = E;
    int iA = e0 + tid * 4;
    int cA = e1 - iA; if (cA > 4) cA = 4; if (cA < 0) cA = 0;

    unsigned pk0=0,pk1=0,pk2=0,pk3=0;
    int bk0=0,bk1=0,bk2=0,bk3=0;
    int rk0=0,rk1=0,rk2=0,rk3=0;
    if (cA == 4) {
        int4 s4 = *reinterpret_cast<const int4*>(src + iA);
        int4 d4 = *reinterpret_cast<const int4*>(dst + iA);
        pk0 = (unsigned)s4.x | ((unsigned)(d4.x & (RNODES-1)) << 17);
        pk1 = (unsigned)s4.y | ((unsigned)(d4.y & (RNODES-1)) << 17);
        pk2 = (unsigned)s4.z | ((unsigned)(d4.z & (RNODES-1)) << 17);
        pk3 = (unsigned)s4.w | ((unsigned)(d4.w & (RNODES-1)) << 17);
        bk0 = d4.x >> RSHIFT; bk1 = d4.y >> RSHIFT;
        bk2 = d4.z >> RSHIFT; bk3 = d4.w >> RSHIFT;
        rk0 = atomicAdd(&hist[bk0], 1);
        rk1 = atomicAdd(&hist[bk1], 1);
        rk2 = atomicAdd(&hist[bk2], 1);
        rk3 = atomicAdd(&hist[bk3], 1);
    } else {
        if (cA > 0) { int s=src[iA],   d=dst[iA];   pk0=(unsigned)s|((unsigned)(d&(RNODES-1))<<17); bk0=d>>RSHIFT; rk0=atomicAdd(&hist[bk0],1); }
        if (cA > 1) { int s=src[iA+1], d=dst[iA+1]; pk1=(unsigned)s|((unsigned)(d&(RNODES-1))<<17); bk1=d>>RSHIFT; rk1=atomicAdd(&hist[bk1],1); }
        if (cA > 2) { int s=src[iA+2], d=dst[iA+2]; pk2=(unsigned)s|((unsigned)(d&(RNODES-1))<<17); bk2=d>>RSHIFT; rk2=atomicAdd(&hist[bk2],1); }
    }
    __syncthreads();
    // reserve each bucket's slab segment for this tile
    {
        int b0 = tid, b1 = tid + STHREADS;
        int h0 = hist[b0], h1 = hist[b1];
        if (h0 > 0) lbase[b0] = atomicAdd(&cursor[b0], h0);
        if (h1 > 0) lbase[b1] = atomicAdd(&cursor[b1], h1);
    }
    __syncthreads();
    if (cA > 0) binned[(size_t)bk0 * BCAP + lbase[bk0] + rk0] = pk0;
    if (cA > 1) binned[(size_t)bk1 * BCAP + lbase[bk1] + rk1] = pk1;
    if (cA > 2) binned[(size_t)bk2 * BCAP + lbase[bk2] + rk2] = pk2;
    if (cA > 3) binned[(size_t)bk3 * BCAP + lbase[bk3] + rk3] = pk3;
}

// half-bucket in-degree histogram in LDS -> coalesced global atomic add
__global__ __launch_bounds__(CTHREADS, 8)
void degpart_k(const unsigned int* __restrict__ binned,
               const int* __restrict__ cursor,
               int* __restrict__ degG, int n) {
    __shared__ int cnt[RNODES];
    const int tid = threadIdx.x;
    const int b = blockIdx.x >> 1, h = blockIdx.x & 1;
    if (tid < RNODES) cnt[tid] = 0;
    __syncthreads();
    size_t s0 = (size_t)b * BCAP;
    int c = cursor[b];
    if (c > BCAP) c = BCAP;
    int mid = ((c >> 1) + 3) & ~3; if (mid > c) mid = c;
    int lo = h ? mid : 0, hi = h ? c : mid;
    int len = hi - lo, nq = len >> 2;
    for (int k = tid; k < nq; k += CTHREADS) {
        uint4 p = *reinterpret_cast<const uint4*>(binned + s0 + lo + 4 * (size_t)k);
        atomicAdd(&cnt[p.x >> 17], 1);
        atomicAdd(&cnt[p.y >> 17], 1);
        atomicAdd(&cnt[p.z >> 17], 1);
        atomicAdd(&cnt[p.w >> 17], 1);
    }
    for (int i = lo + 4 * nq + tid; i < hi; i += CTHREADS)
        atomicAdd(&cnt[binned[s0 + i] >> 17], 1);
    __syncthreads();
    if (tid < RNODES) {
        int g = (b << RSHIFT) + tid;
        if (g < n && cnt[tid] != 0) atomicAdd(&degG[g], cnt[tid]);
    }
}

// dinv = rsqrt(deg+1); w = dinv*u; out init
__global__ __launch_bounds__(CTHREADS, 8)
void finA_k(const int* __restrict__ degG, const float* __restrict__ u,
            const float* __restrict__ scG,
            float* __restrict__ dinv, float* __restrict__ w,
            float* __restrict__ out, int n, int G) {
    int g = blockIdx.x * CTHREADS + threadIdx.x;
    if (blockIdx.x == 0 && threadIdx.x < G) out[threadIdx.x] = scG[2];
    if (g < n) {
        float d = rsqrtf((float)(degG[g] + 1));
        dinv[g] = d;
        w[g] = d * u[g];
    }
}

// half-bucket gather+accumulate of w[src] -> coalesced global float atomics
__global__ __launch_bounds__(CTHREADS, 8)
void midpart_k(const unsigned int* __restrict__ binned,
               const int* __restrict__ cursor,
               const float* __restrict__ w,
               float* __restrict__ accG, int n) {
    __shared__ float acc[RNODES];
    const int tid = threadIdx.x;
    const int b = blockIdx.x >> 1, h = blockIdx.x & 1;
    if (tid < RNODES) acc[tid] = 0.f;
    __syncthreads();
    size_t s0 = (size_t)b * BCAP;
    int c = cursor[b];
    if (c > BCAP) c = BCAP;
    int mid = ((c >> 1) + 3) & ~3; if (mid > c) mid = c;
    int lo = h ? mid : 0, hi = h ? c : mid;
    int len = hi - lo, nq = len >> 2;
    for (int k = tid; k < nq; k += CTHREADS) {
        uint4 p = *reinterpret_cast<const uint4*>(binned + s0 + lo + 4 * (size_t)k);
        float w0 = w[p.x & 0x1FFFF];
        float w1 = w[p.y & 0x1FFFF];
        float w2 = w[p.z & 0x1FFFF];
        float w3 = w[p.w & 0x1FFFF];
        atomicAdd(&acc[p.x >> 17], w0);
        atomicAdd(&acc[p.y >> 17], w1);
        atomicAdd(&acc[p.z >> 17], w2);
        atomicAdd(&acc[p.w >> 17], w3);
    }
    for (int i = lo + 4 * nq + tid; i < hi; i += CTHREADS) {
        unsigned p = binned[s0 + i];
        atomicAdd(&acc[p >> 17], w[p & 0x1FFFF]);
    }
    __syncthreads();
    if (tid < RNODES) {
        int g = (b << RSHIFT) + tid;
        if (g < n && acc[tid] != 0.f) atomicAdd(&accG[g], acc[tid]);
    }
}

// v = c1 + dinv*accG + dinv^2*u ; wb = dinv*v
__global__ __launch_bounds__(CTHREADS, 8)
void finB_k(const float* __restrict__ accG, const float* __restrict__ dinv,
            const float* __restrict__ u, const float* __restrict__ scG,
            float* __restrict__ v, float* __restrict__ wb, int n) {
    int g = blockIdx.x * CTHREADS + threadIdx.x;
    if (g < n) {
        float d = dinv[g];
        float val = scG[0] + d * accG[g] + d * d * u[g];
        v[g] = val;
        wb[g] = d * val;
    }
}

// half-bucket gather+accumulate of wb[src] -> acc2G
__global__ __launch_bounds__(CTHREADS, 8)
void finalpart_k(const unsigned int* __restrict__ binned,
                 const int* __restrict__ cursor,
                 const float* __restrict__ wbv,
                 float* __restrict__ acc2G, int n) {
    __shared__ float acc[RNODES];
    const int tid = threadIdx.x;
    const int b = blockIdx.x >> 1, h = blockIdx.x & 1;
    if (tid < RNODES) acc[tid] = 0.f;
    __syncthreads();
    size_t s0 = (size_t)b * BCAP;
    int c = cursor[b];
    if (c > BCAP) c = BCAP;
    int mid = ((c >> 1) + 3) & ~3; if (mid > c) mid = c;
    int lo = h ? mid : 0, hi = h ? c : mid;
    int len = hi - lo, nq = len >> 2;
    for (int k = tid; k < nq; k += CTHREADS) {
        uint4 p = *reinterpret_cast<const uint4*>(binned + s0 + lo + 4 * (size_t)k);
        float w0 = wbv[p.x & 0x1FFFF];
        float w1 = wbv[p.y & 0x1FFFF];
        float w2 = wbv[p.z & 0x1FFFF];
        float w3 = wbv[p.w & 0x1FFFF];
        atomicAdd(&acc[p.x >> 17], w0);
        atomicAdd(&acc[p.y >> 17], w1);
        atomicAdd(&acc[p.z >> 17], w2);
        atomicAdd(&acc[p.w >> 17], w3);
    }
    for (int i = lo + 4 * nq + tid; i < hi; i += CTHREADS) {
        unsigned p = binned[s0 + i];
        atomicAdd(&acc[p >> 17], wbv[p & 0x1FFFF]);
    }
    __syncthreads();
    if (tid < RNODES) {
        int g = (b << RSHIFT) + tid;
        if (g < n && acc[tid] != 0.f) atomicAdd(&acc2G[g], acc[tid]);
    }
}

// t = c2 + dinv*acc2G + dinv^2*v, segmented pool by sorted batch id
__global__ __launch_bounds__(CTHREADS, 8)
void finC_k(const float* __restrict__ acc2G, const float* __restrict__ dinv,
            const float* __restrict__ v, const float* __restrict__ scG,
            const int* __restrict__ batch, float* __restrict__ out, int n) {
    __shared__ float tbuf[CTHREADS];
    __shared__ int gbuf[CTHREADS];
    int tid = threadIdx.x;
    int g = blockIdx.x * CTHREADS + tid;
    float tval = 0.f; int gid = -1;
    if (g < n) {
        float d = dinv[g];
        tval = scG[1] + d * acc2G[g] + d * d * v[g];
        gid = batch[g];
    }
    tbuf[tid] = tval; gbuf[tid] = gid;
    __syncthreads();
    if (g < n) {
        bool head = (tid == 0) || (gbuf[tid - 1] != gid);
        if (head) {
            float s = 0.f;
            int i2 = tid;
            while (i2 < CTHREADS && gbuf[i2] == gid) { s += tbuf[i2]; ++i2; }
            atomicAdd(&out[gid], s);
        }
    }
}

extern "C" void kernel_launch(void* const* d_in, const int* in_sizes, int n_in,
                              void* d_out, int out_size, void* d_ws, size_t ws_size,
                              hipStream_t stream)
{
    const float* x    = (const float*)d_in[0];
    const int*   ei   = (const int*)d_in[1];
    const int*   batch= (const int*)d_in[2];
    const float* W1   = (const float*)d_in[3];
    const float* b1   = (const float*)d_in[4];
    const float* W2   = (const float*)d_in[5];
    const float* b2   = (const float*)d_in[6];
    const float* Wf1  = (const float*)d_in[7];
    const float* bf1  = (const float*)d_in[8];
    const float* Wf2  = (const float*)d_in[9];
    const float* bf2  = (const float*)d_in[10];
    const float* Wf3  = (const float*)d_in[11];
    const float* bf3  = (const float*)d_in[12];
    const float* Wo   = (const float*)d_in[13];
    const float* bo   = (const float*)d_in[14];
    float* out = (float*)d_out;

    const int n = in_sizes[0] / 64;
    const int E = in_sizes[1] / 2;
    const int G = out_size;
    const int* src = ei;
    const int* dst = ei + E;
    const int nb = (n + RNODES - 1) >> RSHIFT;

    // workspace layout (element offsets)
    float* ws_f = (float*)d_ws;
    int*   ws_i = (int*)d_ws;
    int*   cursor = ws_i;                    // NB_MAX (zeroed by memset)
    float* scG    = ws_f + NB_MAX;           // 3 (+pad to 16)
    size_t off_u  = NB_MAX + 16;
    float* u      = ws_f + off_u;            // n
    float* dinv   = u + n;                   // n
    float* w      = dinv + n;                // n
    float* v      = w + n;                   // n
    float* wb     = v + n;                   // n
    int*   degG   = ws_i + off_u + 5*(size_t)n;   // n
    float* accG   = ws_f + off_u + 6*(size_t)n;   // n
    float* acc2G  = accG + n;                      // n
    size_t off_b  = off_u + 8*(size_t)n;
    off_b = (off_b + 3) & ~(size_t)3;
    unsigned int* binned = (unsigned int*)(ws_f + off_b);   // nb * BCAP

    const int NT = (E + TILE_E - 1) / TILE_E;        // scatter tiles (~1563)
    const int npb = (n + NT - 1) / NT;               // nodes per tile
    const int NN = (n + CTHREADS - 1) / CTHREADS;    // n-scale grids

    hipMemsetAsync(cursor, 0, NB_MAX * sizeof(int), stream);
    hipLaunchKernelGGL(scatter_k, dim3(NT), dim3(STHREADS), 0, stream,
                       x, src, dst,
                       W1, b1, W2, b2, Wf1, bf1, Wf2, bf2, Wf3, bf3, Wo, bo,
                       u, scG, degG, accG, acc2G, E, n, npb, nb, cursor, binned);
    hipLaunchKernelGGL(degpart_k, dim3(2 * nb), dim3(CTHREADS), 0, stream,
                       binned, cursor, degG, n);
    hipLaunchKernelGGL(finA_k, dim3(NN), dim3(CTHREADS), 0, stream,
                       degG, u, scG, dinv, w, out, n, G);
    hipLaunchKernelGGL(midpart_k, dim3(2 * nb), dim3(CTHREADS), 0, stream,
                       binned, cursor, w, accG, n);
    hipLaunchKernelGGL(finB_k, dim3(NN), dim3(CTHREADS), 0, stream,
                       accG, dinv, u, scG, v, wb, n);
    hipLaunchKernelGGL(finalpart_k, dim3(2 * nb), dim3(CTHREADS), 0, stream,
                       binned, cursor, wb, acc2G, n);
    hipLaunchKernelGGL(finC_k, dim3(NN), dim3(CTHREADS), 0, stream,
                       acc2G, dinv, v, scG, batch, out, n);
}

// Round 11
// 210.523 us; speedup vs baseline: 1.1990x; 1.1990x over previous
//
#include <hip/hip_runtime.h>

// GCN edge predictor, collapsed to scalar-per-node linear algebra:
//   u_i = x_i . w1c ;  v = A u + c1 ;  t = A v + c2 ;  out[g] = sum_g t + c0
//   A = D^-1/2 (Adj + I) D^-1/2
// R14 (resubmit; prior bench died on container infra): R12 4-pass structure
//   with the scatter geometry fixed to the measured optimum (782 tiles of
//   4096 edges; R12's 391 tiles ran 1.5 blocks/CU at 46us, R13's 1563 tiles
//   regressed to 66us from per-tile overheads).
//   Pipeline: memset(4KB cursor) + scatter(collapse+u+direct-store) +
//   sort_dinv + conv_mid(+out init) + conv_final.

#define RSHIFT 7
#define RNODES 128           // nodes per bucket
#define NB_MAX 1024          // max buckets (n <= 131072; src fits 17 bits)
#define STHREADS 512
#define CTHREADS 1024        // sort/conv threads
#define TILE_E 4096          // edges per scatter tile (8 per thread)
#define BCAP 6144            // per-bucket slab capacity (mean ~4092, +32 sigma)

// Fused: weight collapse (block-redundant) + u + single-pass direct scatter.
__global__ __launch_bounds__(STHREADS, 8)
void scatter_k(const float* __restrict__ x,
               const int* __restrict__ src, const int* __restrict__ dst,
               const float* __restrict__ W1, const float* __restrict__ b1,
               const float* __restrict__ W2, const float* __restrict__ b2,
               const float* __restrict__ Wf1, const float* __restrict__ bf1,
               const float* __restrict__ Wf2, const float* __restrict__ bf2,
               const float* __restrict__ Wf3, const float* __restrict__ bf3,
               const float* __restrict__ Wo, const float* __restrict__ bo,
               float* __restrict__ u, float* __restrict__ scG,
               int E, int n, int npb, int nb,
               int* __restrict__ cursor, unsigned int* __restrict__ binned) {
    __shared__ int hist[NB_MAX];
    __shared__ int lbase[NB_MAX];
    __shared__ float wtmp[224];
    __shared__ float w1c_s[64];
    const int tid = threadIdx.x;
    const int bx = blockIdx.x;

    // ---- weight collapse (redundant per block; ~9K MACs) ----
    {
        float* wo  = wtmp;         // 10
        float* w3  = wtmp + 16;    // 20
        float* w2  = wtmp + 48;    // 30
        float* w1  = wtmp + 80;    // 50
        float* w2c = wtmp + 144;   // 60
        hist[tid] = 0; hist[tid + STHREADS] = 0;
        if (tid < 10) wo[tid] = Wo[tid];
        __syncthreads();
        if (tid < 20) { float s = 0.f; for (int j = 0; j < 10; ++j) s += Wf3[tid*10+j]*wo[j]; w3[tid] = s; }
        __syncthreads();
        if (tid < 30) { float s = 0.f; for (int j = 0; j < 20; ++j) s += Wf2[tid*20+j]*w3[j]; w2[tid] = s; }
        __syncthreads();
        if (tid < 50) { float s = 0.f; for (int j = 0; j < 30; ++j) s += Wf1[tid*30+j]*w2[j]; w1[tid] = s; }
        __syncthreads();
        if (tid < 60) { float s = 0.f; for (int j = 0; j < 50; ++j) s += W2[tid*50+j]*w1[j]; w2c[tid] = s; }
        __syncthreads();
        if (tid < 64) { float s = 0.f; for (int j = 0; j < 60; ++j) s += W1[tid*60+j]*w2c[j]; w1c_s[tid] = s; }
        if (bx == 0 && tid == 0) {
            float c1 = 0.f; for (int j = 0; j < 60; ++j) c1 += b1[j]*w2c[j];
            float c2 = 0.f; for (int j = 0; j < 50; ++j) c2 += b2[j]*w1[j];
            float c0 = bo[0];
            for (int j = 0; j < 30; ++j) c0 += bf1[j]*w2[j];
            for (int j = 0; j < 20; ++j) c0 += bf2[j]*w3[j];
            for (int j = 0; j < 10; ++j) c0 += bf3[j]*wo[j];
            scG[0] = c1; scG[1] = c2; scG[2] = c0;
        }
        __syncthreads();
    }

    // ---- u for nodes [bx*npb, bx*npb+npb) ----
    {
        const int grp = tid >> 4, sub = tid & 15;
        float4 wv = *reinterpret_cast<const float4*>(&w1c_s[sub * 4]);
        int base = bx * npb;
        for (int p = 0; p * 32 < npb; ++p) {
            int nl = p * 32 + grp;
            int g = base + nl;
            bool ok = (nl < npb) && (g < n);
            float val = 0.f;
            if (ok) {
                float4 xv = *reinterpret_cast<const float4*>(
                    x + (size_t)g * 64 + sub * 4);
                val = xv.x*wv.x + xv.y*wv.y + xv.z*wv.z + xv.w*wv.w;
            }
            val += __shfl_down(val, 8, 16);
            val += __shfl_down(val, 4, 16);
            val += __shfl_down(val, 2, 16);
            val += __shfl_down(val, 1, 16);
            if (ok && sub == 0) u[g] = val;
        }
    }

    // ---- scatter tile bx: 8 edges/thread, 2 named quad groups ----
    int e0 = bx * TILE_E;
    int e1 = e0 + TILE_E; if (e1 > E) e1 = E;

    unsigned pk0=0,pk1=0,pk2=0,pk3=0,pk4=0,pk5=0,pk6=0,pk7=0;
    int bk0=0,bk1=0,bk2=0,bk3=0,bk4=0,bk5=0,bk6=0,bk7=0;
    int rk0=0,rk1=0,rk2=0,rk3=0,rk4=0,rk5=0,rk6=0,rk7=0;
    int iA = e0 + tid * 4;
    int iB = iA + STHREADS * 4;
    int cA = e1 - iA; if (cA > 4) cA = 4; if (cA < 0) cA = 0;
    int cB = e1 - iB; if (cB > 4) cB = 4; if (cB < 0) cB = 0;

    if (cA == 4) {
        int4 s4 = *reinterpret_cast<const int4*>(src + iA);
        int4 d4 = *reinterpret_cast<const int4*>(dst + iA);
        pk0 = (unsigned)s4.x | ((unsigned)(d4.x & (RNODES-1)) << 17);
        pk1 = (unsigned)s4.y | ((unsigned)(d4.y & (RNODES-1)) << 17);
        pk2 = (unsigned)s4.z | ((unsigned)(d4.z & (RNODES-1)) << 17);
        pk3 = (unsigned)s4.w | ((unsigned)(d4.w & (RNODES-1)) << 17);
        bk0 = d4.x >> RSHIFT; bk1 = d4.y >> RSHIFT;
        bk2 = d4.z >> RSHIFT; bk3 = d4.w >> RSHIFT;
        rk0 = atomicAdd(&hist[bk0], 1);
        rk1 = atomicAdd(&hist[bk1], 1);
        rk2 = atomicAdd(&hist[bk2], 1);
        rk3 = atomicAdd(&hist[bk3], 1);
    } else {
        if (cA > 0) { int s=src[iA],   d=dst[iA];   pk0=(unsigned)s|((unsigned)(d&(RNODES-1))<<17); bk0=d>>RSHIFT; rk0=atomicAdd(&hist[bk0],1); }
        if (cA > 1) { int s=src[iA+1], d=dst[iA+1]; pk1=(unsigned)s|((unsigned)(d&(RNODES-1))<<17); bk1=d>>RSHIFT; rk1=atomicAdd(&hist[bk1],1); }
        if (cA > 2) { int s=src[iA+2], d=dst[iA+2]; pk2=(unsigned)s|((unsigned)(d&(RNODES-1))<<17); bk2=d>>RSHIFT; rk2=atomicAdd(&hist[bk2],1); }
    }
    if (cB == 4) {
        int4 s4 = *reinterpret_cast<const int4*>(src + iB);
        int4 d4 = *reinterpret_cast<const int4*>(dst + iB);
        pk4 = (unsigned)s4.x | ((unsigned)(d4.x & (RNODES-1)) << 17);
        pk5 = (unsigned)s4.y | ((unsigned)(d4.y & (RNODES-1)) << 17);
        pk6 = (unsigned)s4.z | ((unsigned)(d4.z & (RNODES-1)) << 17);
        pk7 = (unsigned)s4.w | ((unsigned)(d4.w & (RNODES-1)) << 17);
        bk4 = d4.x >> RSHIFT; bk5 = d4.y >> RSHIFT;
        bk6 = d4.z >> RSHIFT; bk7 = d4.w >> RSHIFT;
        rk4 = atomicAdd(&hist[bk4], 1);
        rk5 = atomicAdd(&hist[bk5], 1);
        rk6 = atomicAdd(&hist[bk6], 1);
        rk7 = atomicAdd(&hist[bk7], 1);
    } else {
        if (cB > 0) { int s=src[iB],   d=dst[iB];   pk4=(unsigned)s|((unsigned)(d&(RNODES-1))<<17); bk4=d>>RSHIFT; rk4=atomicAdd(&hist[bk4],1); }
        if (cB > 1) { int s=src[iB+1], d=dst[iB+1]; pk5=(unsigned)s|((unsigned)(d&(RNODES-1))<<17); bk5=d>>RSHIFT; rk5=atomicAdd(&hist[bk5],1); }
        if (cB > 2) { int s=src[iB+2], d=dst[iB+2]; pk6=(unsigned)s|((unsigned)(d&(RNODES-1))<<17); bk6=d>>RSHIFT; rk6=atomicAdd(&hist[bk6],1); }
    }
    __syncthreads();

    // reserve each bucket's slab segment for this tile
    {
        int b0 = tid, b1 = tid + STHREADS;
        int h0 = hist[b0], h1 = hist[b1];
        if (h0 > 0) lbase[b0] = atomicAdd(&cursor[b0], h0);
        if (h1 > 0) lbase[b1] = atomicAdd(&cursor[b1], h1);
    }
    __syncthreads();

    if (cA > 0) binned[(size_t)bk0 * BCAP + lbase[bk0] + rk0] = pk0;
    if (cA > 1) binned[(size_t)bk1 * BCAP + lbase[bk1] + rk1] = pk1;
    if (cA > 2) binned[(size_t)bk2 * BCAP + lbase[bk2] + rk2] = pk2;
    if (cA > 3) binned[(size_t)bk3 * BCAP + lbase[bk3] + rk3] = pk3;
    if (cB > 0) binned[(size_t)bk4 * BCAP + lbase[bk4] + rk4] = pk4;
    if (cB > 1) binned[(size_t)bk5 * BCAP + lbase[bk5] + rk5] = pk5;
    if (cB > 2) binned[(size_t)bk6 * BCAP + lbase[bk6] + rk6] = pk6;
    if (cB > 3) binned[(size_t)bk7 * BCAP + lbase[bk7] + rk7] = pk7;
}

// Sort bucket edges by destination node in LDS; emit node-sorted bucket,
// per-node within-bucket offsets, dinv = rsqrt(deg+1), w = dinv*u.
__global__ __launch_bounds__(CTHREADS, 2)
void sort_dinv_k(unsigned int* __restrict__ binned,
                 const int* __restrict__ cursor,
                 const float* __restrict__ u,
                 float* __restrict__ dinv, float* __restrict__ w,
                 int* __restrict__ offG, int n) {
    __shared__ unsigned eIn[BCAP];    // 24 KB
    __shared__ unsigned eOut[BCAP];   // 24 KB
    __shared__ int cnt[RNODES];
    __shared__ int off[RNODES];
    __shared__ int pos[RNODES];
    const int tid = threadIdx.x, b = blockIdx.x;
    if (tid < RNODES) cnt[tid] = 0;
    __syncthreads();
    size_t s0 = (size_t)b * BCAP;
    int c = cursor[b];
    if (c > BCAP) c = BCAP;
    int nvec = c >> 2;
    // load + count fused
    for (int k = tid; k < nvec; k += CTHREADS) {
        uint4 p = *reinterpret_cast<const uint4*>(binned + s0 + 4 * (size_t)k);
        eIn[4*k+0] = p.x; eIn[4*k+1] = p.y; eIn[4*k+2] = p.z; eIn[4*k+3] = p.w;
        atomicAdd(&cnt[p.x >> 17], 1);
        atomicAdd(&cnt[p.y >> 17], 1);
        atomicAdd(&cnt[p.z >> 17], 1);
        atomicAdd(&cnt[p.w >> 17], 1);
    }
    for (int i = 4 * nvec + tid; i < c; i += CTHREADS) {
        unsigned p = binned[s0 + i];
        eIn[i] = p;
        atomicAdd(&cnt[p >> 17], 1);
    }
    __syncthreads();
    // 128-entry exclusive scan (Hillis-Steele)
    int hval = (tid < RNODES) ? cnt[tid] : 0;
    if (tid < RNODES) off[tid] = hval;
    __syncthreads();
    for (int o = 1; o < RNODES; o <<= 1) {
        int a = 0;
        if (tid < RNODES && tid >= o) a = off[tid - o];
        __syncthreads();
        if (tid < RNODES) off[tid] += a;
        __syncthreads();
    }
    if (tid < RNODES) {
        int e = off[tid] - hval;   // exclusive
        off[tid] = e;
        pos[tid] = e;
    }
    __syncthreads();
    // rank + scatter into node-sorted order
    for (int i = tid; i < c; i += CTHREADS) {
        unsigned p = eIn[i];
        int r = atomicAdd(&pos[p >> 17], 1);
        eOut[r] = p;
    }
    __syncthreads();
    // write back (vectorized) + per-node outputs
    for (int k = tid; k < nvec; k += CTHREADS) {
        uint4 p;
        p.x = eOut[4*k+0]; p.y = eOut[4*k+1]; p.z = eOut[4*k+2]; p.w = eOut[4*k+3];
        *reinterpret_cast<uint4*>(binned + s0 + 4 * (size_t)k) = p;
    }
    for (int i = 4 * nvec + tid; i < c; i += CTHREADS)
        binned[s0 + i] = eOut[i];
    if (tid < RNODES) {
        int g = (b << RSHIFT) + tid;
        if (g < n) {
            float d = rsqrtf((float)(cnt[tid] + 1));
            dinv[g] = d;
            w[g] = d * u[g];
            offG[g] = off[tid];
        }
    }
}

// v = c1 + dinv*(sum of w[src] over node's contiguous segment) + dinv^2*u
// 8 lanes per node, register accumulation, shfl reduce. Also out[g] = c0.
__global__ __launch_bounds__(CTHREADS, 2)
void conv_mid_k(const unsigned int* __restrict__ binned,
                const int* __restrict__ cursor, const int* __restrict__ offG,
                const float* __restrict__ w, const float* __restrict__ dinv,
                const float* __restrict__ u, const float* __restrict__ sc,
                float* __restrict__ v, float* __restrict__ wb,
                float* __restrict__ out, int n, int G) {
    __shared__ int off_s[RNODES + 1];
    int tid = threadIdx.x, b = blockIdx.x;
    if (b == 0 && tid < G) out[tid] = sc[2];
    size_t s0 = (size_t)b * BCAP;
    int c = cursor[b];
    if (c > BCAP) c = BCAP;
    if (tid < RNODES) {
        int g = (b << RSHIFT) + tid;
        off_s[tid] = (g < n) ? offG[g] : c;
    }
    if (tid == 0) off_s[RNODES] = c;
    __syncthreads();
    int node = tid >> 3, sub = tid & 7;
    int g = (b << RSHIFT) + node;
    int o0 = off_s[node], o1 = off_s[node + 1];
    float s = 0.f;
    for (int k = o0 + sub; k < o1; k += 8) {
        unsigned p = binned[s0 + k];
        s += w[p & 0x1FFFF];
    }
    s += __shfl_xor(s, 1, 8);
    s += __shfl_xor(s, 2, 8);
    s += __shfl_xor(s, 4, 8);
    if (sub == 0 && g < n) {
        float di = dinv[g];
        float val = sc[0] + di * s + di * di * u[g];
        v[g] = val;
        wb[g] = di * val;
    }
}

// t = c2 + dinv*sum + dinv^2*v, then segmented pool by sorted batch id
__global__ __launch_bounds__(CTHREADS, 2)
void conv_final_k(const unsigned int* __restrict__ binned,
                  const int* __restrict__ cursor, const int* __restrict__ offG,
                  const float* __restrict__ wbv, const float* __restrict__ dinv,
                  const float* __restrict__ v, const float* __restrict__ sc,
                  const int* __restrict__ batch, float* __restrict__ out, int n) {
    __shared__ int off_s[RNODES + 1];
    __shared__ float tbuf[RNODES];
    __shared__ int gbuf[RNODES];
    int tid = threadIdx.x, b = blockIdx.x;
    size_t s0 = (size_t)b * BCAP;
    int c = cursor[b];
    if (c > BCAP) c = BCAP;
    if (tid < RNODES) {
        int g = (b << RSHIFT) + tid;
        off_s[tid] = (g < n) ? offG[g] : c;
    }
    if (tid == 0) off_s[RNODES] = c;
    __syncthreads();
    int node = tid >> 3, sub = tid & 7;
    int g = (b << RSHIFT) + node;
    int o0 = off_s[node], o1 = off_s[node + 1];
    float s = 0.f;
    for (int k = o0 + sub; k < o1; k += 8) {
        unsigned p = binned[s0 + k];
        s += wbv[p & 0x1FFFF];
    }
    s += __shfl_xor(s, 1, 8);
    s += __shfl_xor(s, 2, 8);
    s += __shfl_xor(s, 4, 8);
    if (sub == 0) {
        float tval = 0.f; int gid = -1;
        if (g < n) {
            float di = dinv[g];
            tval = sc[1] + di * s + di * di * v[g];
            gid = batch[g];
        }
        tbuf[node] = tval;
        gbuf[node] = gid;
    }
    __syncthreads();
    if (tid < RNODES) {
        int g2 = (b << RSHIFT) + tid;
        if (g2 < n) {
            int gid = gbuf[tid];
            bool head = (tid == 0) || (gbuf[tid - 1] != gid);
            if (head) {
                float sum = 0.f;
                int i2 = tid;
                while (i2 < RNODES && gbuf[i2] == gid) { sum += tbuf[i2]; ++i2; }
                atomicAdd(&out[gid], sum);
            }
        }
    }
}

extern "C" void kernel_launch(void* const* d_in, const int* in_sizes, int n_in,
                              void* d_out, int out_size, void* d_ws, size_t ws_size,
                              hipStream_t stream)
{
    const float* x    = (const float*)d_in[0];
    const int*   ei   = (const int*)d_in[1];
    const int*   batch= (const int*)d_in[2];
    const float* W1   = (const float*)d_in[3];
    const float* b1   = (const float*)d_in[4];
    const float* W2   = (const float*)d_in[5];
    const float* b2   = (const float*)d_in[6];
    const float* Wf1  = (const float*)d_in[7];
    const float* bf1  = (const float*)d_in[8];
    const float* Wf2  = (const float*)d_in[9];
    const float* bf2  = (const float*)d_in[10];
    const float* Wf3  = (const float*)d_in[11];
    const float* bf3  = (const float*)d_in[12];
    const float* Wo   = (const float*)d_in[13];
    const float* bo   = (const float*)d_in[14];
    float* out = (float*)d_out;

    const int n = in_sizes[0] / 64;
    const int E = in_sizes[1] / 2;
    const int G = out_size;
    const int* src = ei;
    const int* dst = ei + E;
    const int nb = (n + RNODES - 1) >> RSHIFT;

    // workspace layout (element offsets)
    float* ws_f = (float*)d_ws;
    int*   ws_i = (int*)d_ws;
    int*   cursor = ws_i;                    // NB_MAX (zeroed by memset)
    float* scG    = ws_f + NB_MAX;           // 3 (+pad to 16)
    size_t off_u  = NB_MAX + 16;
    float* u      = ws_f + off_u;            // n
    float* dinv   = u + n;                   // n
    float* w      = dinv + n;                // n
    float* v      = w + n;                   // n
    float* wb     = v + n;                   // n
    int*   offG   = ws_i + off_u + 5*(size_t)n;   // n
    size_t off_b  = off_u + 6*(size_t)n;
    off_b = (off_b + 3) & ~(size_t)3;
    unsigned int* binned = (unsigned int*)(ws_f + off_b);   // nb * BCAP

    const int NT = (E + TILE_E - 1) / TILE_E;        // scatter tiles (~782)
    const int npb = (n + NT - 1) / NT;               // nodes per tile for u

    hipMemsetAsync(cursor, 0, NB_MAX * sizeof(int), stream);
    hipLaunchKernelGGL(scatter_k, dim3(NT), dim3(STHREADS), 0, stream,
                       x, src, dst,
                       W1, b1, W2, b2, Wf1, bf1, Wf2, bf2, Wf3, bf3, Wo, bo,
                       u, scG, E, n, npb, nb, cursor, binned);
    hipLaunchKernelGGL(sort_dinv_k, dim3(nb), dim3(CTHREADS), 0, stream,
                       binned, cursor, u, dinv, w, offG, n);
    hipLaunchKernelGGL(conv_mid_k, dim3(nb), dim3(CTHREADS), 0, stream,
                       binned, cursor, offG, w, dinv, u, scG, v, wb, out, n, G);
    hipLaunchKernelGGL(conv_final_k, dim3(nb), dim3(CTHREADS), 0, stream,
                       binned, cursor, offG, wb, dinv, v, scG, batch, out, n);
}

// Round 12
// 197.482 us; speedup vs baseline: 1.2782x; 1.0660x over previous
//
#include <hip/hip_runtime.h>

// GCN edge predictor, collapsed to scalar-per-node linear algebra:
//   u_i = x_i . w1c ;  v = A u + c1 ;  t = A v + c2 ;  out[g] = sum_g t + c0
//   A = D^-1/2 (Adj + I) D^-1/2
// R15: R12's minimal 4-kernel pipeline + LDS-staged DENSE-FLUSH scatter.
//   Evidence: direct-store scatter writes 46-58MB (4B scattered stores,
//   32B-sector amplification, duration tracks write traffic not occupancy);
//   the R8/R10 staged flush measured ~14MB (coalesced runs). Named-scalar
//   macro staging (16 edges/thread, 391 tiles) keeps it spill-free.
//   Pipeline: memset(4KB cursor) + scatter(collapse+u+staged flush) +
//   sort_dinv + conv_mid(+out init) + conv_final.

#define RSHIFT 7
#define RNODES 128           // nodes per bucket
#define NB_MAX 1024          // max buckets (n <= 131072; src fits 17 bits)
#define STHREADS 512
#define CTHREADS 1024        // sort/conv threads
#define STAGE_CAP 8192       // edges per scatter tile (16 per thread)
#define BCAP 6144            // per-bucket slab capacity (mean ~4092, +32 sigma)

// one quad-group of the scatter staging, all state in caller-named scalars
#define LOAD_QUAD(ii, cc, P0, P1, P2, P3, B0, B1, B2, B3, R0, R1, R2, R3)     \
    if (cc == 4) {                                                            \
        int4 s4 = *reinterpret_cast<const int4*>(src + ii);                   \
        int4 d4 = *reinterpret_cast<const int4*>(dst + ii);                   \
        P0 = (unsigned)s4.x | ((unsigned)(d4.x & (RNODES-1)) << 17);          \
        P1 = (unsigned)s4.y | ((unsigned)(d4.y & (RNODES-1)) << 17);          \
        P2 = (unsigned)s4.z | ((unsigned)(d4.z & (RNODES-1)) << 17);          \
        P3 = (unsigned)s4.w | ((unsigned)(d4.w & (RNODES-1)) << 17);          \
        B0 = d4.x >> RSHIFT; B1 = d4.y >> RSHIFT;                             \
        B2 = d4.z >> RSHIFT; B3 = d4.w >> RSHIFT;                             \
        R0 = atomicAdd(&hist[B0], 1);                                         \
        R1 = atomicAdd(&hist[B1], 1);                                         \
        R2 = atomicAdd(&hist[B2], 1);                                         \
        R3 = atomicAdd(&hist[B3], 1);                                         \
    } else {                                                                  \
        if (cc > 0) { int s=src[ii],   d=dst[ii];   P0=(unsigned)s|((unsigned)(d&(RNODES-1))<<17); B0=d>>RSHIFT; R0=atomicAdd(&hist[B0],1); } \
        if (cc > 1) { int s=src[ii+1], d=dst[ii+1]; P1=(unsigned)s|((unsigned)(d&(RNODES-1))<<17); B1=d>>RSHIFT; R1=atomicAdd(&hist[B1],1); } \
        if (cc > 2) { int s=src[ii+2], d=dst[ii+2]; P2=(unsigned)s|((unsigned)(d&(RNODES-1))<<17); B2=d>>RSHIFT; R2=atomicAdd(&hist[B2],1); } \
    }

#define STORE_QUAD(cc, P0, P1, P2, P3, B0, B1, B2, B3, R0, R1, R2, R3)        \
    if (cc > 0) { int s2 = tbase[B0] + R0; staged[s2] = P0; bof[s2] = (unsigned short)B0; } \
    if (cc > 1) { int s2 = tbase[B1] + R1; staged[s2] = P1; bof[s2] = (unsigned short)B1; } \
    if (cc > 2) { int s2 = tbase[B2] + R2; staged[s2] = P2; bof[s2] = (unsigned short)B2; } \
    if (cc > 3) { int s2 = tbase[B3] + R3; staged[s2] = P3; bof[s2] = (unsigned short)B3; }

// Fused: weight collapse (block-redundant) + u + LDS-staged scatter with
// dense coalesced flush into bucket slabs.
__global__ __launch_bounds__(STHREADS, 4)
void scatter_k(const float* __restrict__ x,
               const int* __restrict__ src, const int* __restrict__ dst,
               const float* __restrict__ W1, const float* __restrict__ b1,
               const float* __restrict__ W2, const float* __restrict__ b2,
               const float* __restrict__ Wf1, const float* __restrict__ bf1,
               const float* __restrict__ Wf2, const float* __restrict__ bf2,
               const float* __restrict__ Wf3, const float* __restrict__ bf3,
               const float* __restrict__ Wo, const float* __restrict__ bo,
               float* __restrict__ u, float* __restrict__ scG,
               int E, int n, int npb, int nb,
               int* __restrict__ cursor, unsigned int* __restrict__ binned) {
    __shared__ int hist[NB_MAX];
    __shared__ int tbase[NB_MAX];
    __shared__ int adj[NB_MAX];
    __shared__ int sums[STHREADS];
    __shared__ unsigned int staged[STAGE_CAP];
    __shared__ unsigned short bof[STAGE_CAP];
    __shared__ float wtmp[224];
    __shared__ float w1c_s[64];
    const int tid = threadIdx.x;
    const int bx = blockIdx.x;

    // ---- weight collapse (redundant per block; ~9K MACs) ----
    {
        float* wo  = wtmp;         // 10
        float* w3  = wtmp + 16;    // 20
        float* w2  = wtmp + 48;    // 30
        float* w1  = wtmp + 80;    // 50
        float* w2c = wtmp + 144;   // 60
        hist[tid] = 0; hist[tid + STHREADS] = 0;
        if (tid < 10) wo[tid] = Wo[tid];
        __syncthreads();
        if (tid < 20) { float s = 0.f; for (int j = 0; j < 10; ++j) s += Wf3[tid*10+j]*wo[j]; w3[tid] = s; }
        __syncthreads();
        if (tid < 30) { float s = 0.f; for (int j = 0; j < 20; ++j) s += Wf2[tid*20+j]*w3[j]; w2[tid] = s; }
        __syncthreads();
        if (tid < 50) { float s = 0.f; for (int j = 0; j < 30; ++j) s += Wf1[tid*30+j]*w2[j]; w1[tid] = s; }
        __syncthreads();
        if (tid < 60) { float s = 0.f; for (int j = 0; j < 50; ++j) s += W2[tid*50+j]*w1[j]; w2c[tid] = s; }
        __syncthreads();
        if (tid < 64) { float s = 0.f; for (int j = 0; j < 60; ++j) s += W1[tid*60+j]*w2c[j]; w1c_s[tid] = s; }
        if (bx == 0 && tid == 0) {
            float c1 = 0.f; for (int j = 0; j < 60; ++j) c1 += b1[j]*w2c[j];
            float c2 = 0.f; for (int j = 0; j < 50; ++j) c2 += b2[j]*w1[j];
            float c0 = bo[0];
            for (int j = 0; j < 30; ++j) c0 += bf1[j]*w2[j];
            for (int j = 0; j < 20; ++j) c0 += bf2[j]*w3[j];
            for (int j = 0; j < 10; ++j) c0 += bf3[j]*wo[j];
            scG[0] = c1; scG[1] = c2; scG[2] = c0;
        }
        __syncthreads();
    }

    // ---- u for nodes [bx*npb, bx*npb+npb) ----
    {
        const int grp = tid >> 4, sub = tid & 15;
        float4 wv = *reinterpret_cast<const float4*>(&w1c_s[sub * 4]);
        int base = bx * npb;
        for (int p = 0; p * 32 < npb; ++p) {
            int nl = p * 32 + grp;
            int g = base + nl;
            bool ok = (nl < npb) && (g < n);
            float val = 0.f;
            if (ok) {
                float4 xv = *reinterpret_cast<const float4*>(
                    x + (size_t)g * 64 + sub * 4);
                val = xv.x*wv.x + xv.y*wv.y + xv.z*wv.z + xv.w*wv.w;
            }
            val += __shfl_down(val, 8, 16);
            val += __shfl_down(val, 4, 16);
            val += __shfl_down(val, 2, 16);
            val += __shfl_down(val, 1, 16);
            if (ok && sub == 0) u[g] = val;
        }
    }

    // ---- scatter tile bx: 16 edges/thread in 4 named quad groups ----
    int e0 = bx * STAGE_CAP;
    int e1 = e0 + STAGE_CAP; if (e1 > E) e1 = E;

    unsigned pa0=0,pa1=0,pa2=0,pa3=0, pb0=0,pb1=0,pb2=0,pb3=0;
    unsigned pc0=0,pc1=0,pc2=0,pc3=0, pd0=0,pd1=0,pd2=0,pd3=0;
    int ba0=0,ba1=0,ba2=0,ba3=0, bb0=0,bb1=0,bb2=0,bb3=0;
    int bc0=0,bc1=0,bc2=0,bc3=0, bd0=0,bd1=0,bd2=0,bd3=0;
    int ra0=0,ra1=0,ra2=0,ra3=0, rb0=0,rb1=0,rb2=0,rb3=0;
    int rc0=0,rc1=0,rc2=0,rc3=0, rd0=0,rd1=0,rd2=0,rd3=0;

    int iA = e0 + tid * 4;
    int iB = iA + STHREADS * 4;
    int iC = iB + STHREADS * 4;
    int iD = iC + STHREADS * 4;
    int cA = e1 - iA; if (cA > 4) cA = 4; if (cA < 0) cA = 0;
    int cB = e1 - iB; if (cB > 4) cB = 4; if (cB < 0) cB = 0;
    int cC = e1 - iC; if (cC > 4) cC = 4; if (cC < 0) cC = 0;
    int cD = e1 - iD; if (cD > 4) cD = 4; if (cD < 0) cD = 0;

    LOAD_QUAD(iA, cA, pa0,pa1,pa2,pa3, ba0,ba1,ba2,ba3, ra0,ra1,ra2,ra3)
    LOAD_QUAD(iB, cB, pb0,pb1,pb2,pb3, bb0,bb1,bb2,bb3, rb0,rb1,rb2,rb3)
    LOAD_QUAD(iC, cC, pc0,pc1,pc2,pc3, bc0,bc1,bc2,bc3, rc0,rc1,rc2,rc3)
    LOAD_QUAD(iD, cD, pd0,pd1,pd2,pd3, bd0,bd1,bd2,bd3, rd0,rd1,rd2,rd3)
    __syncthreads();

    // block-exclusive scan of hist[0..1023] (2 slots per thread)
    int h0 = hist[2*tid], h1 = hist[2*tid+1];
    int pair = h0 + h1;
    sums[tid] = pair;
    __syncthreads();
    for (int off = 1; off < STHREADS; off <<= 1) {
        int a = (tid >= off) ? sums[tid - off] : 0;
        __syncthreads();
        sums[tid] += a;
        __syncthreads();
    }
    int excl = sums[tid] - pair;
    tbase[2*tid] = excl;
    tbase[2*tid+1] = excl + h0;
    // reserve this tile's segment in each bucket's slab
    {
        int b0 = 2*tid, b1 = 2*tid + 1;
        if (b0 < nb && h0 > 0) {
            int r = atomicAdd(&cursor[b0], h0);
            adj[b0] = b0 * BCAP + r - excl;
        }
        if (b1 < nb && h1 > 0) {
            int r = atomicAdd(&cursor[b1], h1);
            adj[b1] = b1 * BCAP + r - (excl + h0);
        }
    }
    __syncthreads();

    STORE_QUAD(cA, pa0,pa1,pa2,pa3, ba0,ba1,ba2,ba3, ra0,ra1,ra2,ra3)
    STORE_QUAD(cB, pb0,pb1,pb2,pb3, bb0,bb1,bb2,bb3, rb0,rb1,rb2,rb3)
    STORE_QUAD(cC, pc0,pc1,pc2,pc3, bc0,bc1,bc2,bc3, rc0,rc1,rc2,rc3)
    STORE_QUAD(cD, pd0,pd1,pd2,pd3, bd0,bd1,bd2,bd3, rd0,rd1,rd2,rd3)
    __syncthreads();

    // dense flush: consecutive LDS slots -> consecutive global addresses
    int tcount = e1 - e0;
    for (int s2 = tid; s2 < tcount; s2 += STHREADS) {
        int b = bof[s2];
        binned[adj[b] + s2] = staged[s2];
    }
}

// Sort bucket edges by destination node in LDS; emit node-sorted bucket,
// per-node within-bucket offsets, dinv = rsqrt(deg+1), w = dinv*u.
__global__ __launch_bounds__(CTHREADS, 2)
void sort_dinv_k(unsigned int* __restrict__ binned,
                 const int* __restrict__ cursor,
                 const float* __restrict__ u,
                 float* __restrict__ dinv, float* __restrict__ w,
                 int* __restrict__ offG, int n) {
    __shared__ unsigned eIn[BCAP];    // 24 KB
    __shared__ unsigned eOut[BCAP];   // 24 KB
    __shared__ int cnt[RNODES];
    __shared__ int off[RNODES];
    __shared__ int pos[RNODES];
    const int tid = threadIdx.x, b = blockIdx.x;
    if (tid < RNODES) cnt[tid] = 0;
    __syncthreads();
    size_t s0 = (size_t)b * BCAP;
    int c = cursor[b];
    if (c > BCAP) c = BCAP;
    int nvec = c >> 2;
    // load + count fused
    for (int k = tid; k < nvec; k += CTHREADS) {
        uint4 p = *reinterpret_cast<const uint4*>(binned + s0 + 4 * (size_t)k);
        eIn[4*k+0] = p.x; eIn[4*k+1] = p.y; eIn[4*k+2] = p.z; eIn[4*k+3] = p.w;
        atomicAdd(&cnt[p.x >> 17], 1);
        atomicAdd(&cnt[p.y >> 17], 1);
        atomicAdd(&cnt[p.z >> 17], 1);
        atomicAdd(&cnt[p.w >> 17], 1);
    }
    for (int i = 4 * nvec + tid; i < c; i += CTHREADS) {
        unsigned p = binned[s0 + i];
        eIn[i] = p;
        atomicAdd(&cnt[p >> 17], 1);
    }
    __syncthreads();
    // 128-entry exclusive scan (Hillis-Steele)
    int hval = (tid < RNODES) ? cnt[tid] : 0;
    if (tid < RNODES) off[tid] = hval;
    __syncthreads();
    for (int o = 1; o < RNODES; o <<= 1) {
        int a = 0;
        if (tid < RNODES && tid >= o) a = off[tid - o];
        __syncthreads();
        if (tid < RNODES) off[tid] += a;
        __syncthreads();
    }
    if (tid < RNODES) {
        int e = off[tid] - hval;   // exclusive
        off[tid] = e;
        pos[tid] = e;
    }
    __syncthreads();
    // rank + scatter into node-sorted order
    for (int i = tid; i < c; i += CTHREADS) {
        unsigned p = eIn[i];
        int r = atomicAdd(&pos[p >> 17], 1);
        eOut[r] = p;
    }
    __syncthreads();
    // write back (vectorized) + per-node outputs
    for (int k = tid; k < nvec; k += CTHREADS) {
        uint4 p;
        p.x = eOut[4*k+0]; p.y = eOut[4*k+1]; p.z = eOut[4*k+2]; p.w = eOut[4*k+3];
        *reinterpret_cast<uint4*>(binned + s0 + 4 * (size_t)k) = p;
    }
    for (int i = 4 * nvec + tid; i < c; i += CTHREADS)
        binned[s0 + i] = eOut[i];
    if (tid < RNODES) {
        int g = (b << RSHIFT) + tid;
        if (g < n) {
            float d = rsqrtf((float)(cnt[tid] + 1));
            dinv[g] = d;
            w[g] = d * u[g];
            offG[g] = off[tid];
        }
    }
}

// v = c1 + dinv*(sum of w[src] over node's contiguous segment) + dinv^2*u
// 8 lanes per node, register accumulation, shfl reduce. Also out[g] = c0.
__global__ __launch_bounds__(CTHREADS, 2)
void conv_mid_k(const unsigned int* __restrict__ binned,
                const int* __restrict__ cursor, const int* __restrict__ offG,
                const float* __restrict__ w, const float* __restrict__ dinv,
                const float* __restrict__ u, const float* __restrict__ sc,
                float* __restrict__ v, float* __restrict__ wb,
                float* __restrict__ out, int n, int G) {
    __shared__ int off_s[RNODES + 1];
    int tid = threadIdx.x, b = blockIdx.x;
    if (b == 0 && tid < G) out[tid] = sc[2];
    size_t s0 = (size_t)b * BCAP;
    int c = cursor[b];
    if (c > BCAP) c = BCAP;
    if (tid < RNODES) {
        int g = (b << RSHIFT) + tid;
        off_s[tid] = (g < n) ? offG[g] : c;
    }
    if (tid == 0) off_s[RNODES] = c;
    __syncthreads();
    int node = tid >> 3, sub = tid & 7;
    int g = (b << RSHIFT) + node;
    int o0 = off_s[node], o1 = off_s[node + 1];
    float s = 0.f;
    for (int k = o0 + sub; k < o1; k += 8) {
        unsigned p = binned[s0 + k];
        s += w[p & 0x1FFFF];
    }
    s += __shfl_xor(s, 1, 8);
    s += __shfl_xor(s, 2, 8);
    s += __shfl_xor(s, 4, 8);
    if (sub == 0 && g < n) {
        float di = dinv[g];
        float val = sc[0] + di * s + di * di * u[g];
        v[g] = val;
        wb[g] = di * val;
    }
}

// t = c2 + dinv*sum + dinv^2*v, then segmented pool by sorted batch id
__global__ __launch_bounds__(CTHREADS, 2)
void conv_final_k(const unsigned int* __restrict__ binned,
                  const int* __restrict__ cursor, const int* __restrict__ offG,
                  const float* __restrict__ wbv, const float* __restrict__ dinv,
                  const float* __restrict__ v, const float* __restrict__ sc,
                  const int* __restrict__ batch, float* __restrict__ out, int n) {
    __shared__ int off_s[RNODES + 1];
    __shared__ float tbuf[RNODES];
    __shared__ int gbuf[RNODES];
    int tid = threadIdx.x, b = blockIdx.x;
    size_t s0 = (size_t)b * BCAP;
    int c = cursor[b];
    if (c > BCAP) c = BCAP;
    if (tid < RNODES) {
        int g = (b << RSHIFT) + tid;
        off_s[tid] = (g < n) ? offG[g] : c;
    }
    if (tid == 0) off_s[RNODES] = c;
    __syncthreads();
    int node = tid >> 3, sub = tid & 7;
    int g = (b << RSHIFT) + node;
    int o0 = off_s[node], o1 = off_s[node + 1];
    float s = 0.f;
    for (int k = o0 + sub; k < o1; k += 8) {
        unsigned p = binned[s0 + k];
        s += wbv[p & 0x1FFFF];
    }
    s += __shfl_xor(s, 1, 8);
    s += __shfl_xor(s, 2, 8);
    s += __shfl_xor(s, 4, 8);
    if (sub == 0) {
        float tval = 0.f; int gid = -1;
        if (g < n) {
            float di = dinv[g];
            tval = sc[1] + di * s + di * di * v[g];
            gid = batch[g];
        }
        tbuf[node] = tval;
        gbuf[node] = gid;
    }
    __syncthreads();
    if (tid < RNODES) {
        int g2 = (b << RSHIFT) + tid;
        if (g2 < n) {
            int gid = gbuf[tid];
            bool head = (tid == 0) || (gbuf[tid - 1] != gid);
            if (head) {
                float sum = 0.f;
                int i2 = tid;
                while (i2 < RNODES && gbuf[i2] == gid) { sum += tbuf[i2]; ++i2; }
                atomicAdd(&out[gid], sum);
            }
        }
    }
}

extern "C" void kernel_launch(void* const* d_in, const int* in_sizes, int n_in,
                              void* d_out, int out_size, void* d_ws, size_t ws_size,
                              hipStream_t stream)
{
    const float* x    = (const float*)d_in[0];
    const int*   ei   = (const int*)d_in[1];
    const int*   batch= (const int*)d_in[2];
    const float* W1   = (const float*)d_in[3];
    const float* b1   = (const float*)d_in[4];
    const float* W2   = (const float*)d_in[5];
    const float* b2   = (const float*)d_in[6];
    const float* Wf1  = (const float*)d_in[7];
    const float* bf1  = (const float*)d_in[8];
    const float* Wf2  = (const float*)d_in[9];
    const float* bf2  = (const float*)d_in[10];
    const float* Wf3  = (const float*)d_in[11];
    const float* bf3  = (const float*)d_in[12];
    const float* Wo   = (const float*)d_in[13];
    const float* bo   = (const float*)d_in[14];
    float* out = (float*)d_out;

    const int n = in_sizes[0] / 64;
    const int E = in_sizes[1] / 2;
    const int G = out_size;
    const int* src = ei;
    const int* dst = ei + E;
    const int nb = (n + RNODES - 1) >> RSHIFT;

    // workspace layout (element offsets)
    float* ws_f = (float*)d_ws;
    int*   ws_i = (int*)d_ws;
    int*   cursor = ws_i;                    // NB_MAX (zeroed by memset)
    float* scG    = ws_f + NB_MAX;           // 3 (+pad to 16)
    size_t off_u  = NB_MAX + 16;
    float* u      = ws_f + off_u;            // n
    float* dinv   = u + n;                   // n
    float* w      = dinv + n;                // n
    float* v      = w + n;                   // n
    float* wb     = v + n;                   // n
    int*   offG   = ws_i + off_u + 5*(size_t)n;   // n
    size_t off_b  = off_u + 6*(size_t)n;
    off_b = (off_b + 3) & ~(size_t)3;
    unsigned int* binned = (unsigned int*)(ws_f + off_b);   // nb * BCAP

    const int NT = (E + STAGE_CAP - 1) / STAGE_CAP;  // scatter tiles (~391)
    const int npb = (n + NT - 1) / NT;               // nodes per tile for u

    hipMemsetAsync(cursor, 0, NB_MAX * sizeof(int), stream);
    hipLaunchKernelGGL(scatter_k, dim3(NT), dim3(STHREADS), 0, stream,
                       x, src, dst,
                       W1, b1, W2, b2, Wf1, bf1, Wf2, bf2, Wf3, bf3, Wo, bo,
                       u, scG, E, n, npb, nb, cursor, binned);
    hipLaunchKernelGGL(sort_dinv_k, dim3(nb), dim3(CTHREADS), 0, stream,
                       binned, cursor, u, dinv, w, offG, n);
    hipLaunchKernelGGL(conv_mid_k, dim3(nb), dim3(CTHREADS), 0, stream,
                       binned, cursor, offG, w, dinv, u, scG, v, wb, out, n, G);
    hipLaunchKernelGGL(conv_final_k, dim3(nb), dim3(CTHREADS), 0, stream,
                       binned, cursor, offG, wb, dinv, v, scG, batch, out, n);
}